// Round 1
// baseline (216.126 us; speedup 1.0000x reference)
//
#include <hip/hip_runtime.h>
#include <math.h>

#define N_LAYERS 4
#define SEQ      34
#define BATCH_N  16384
#define NB       7          // batch elements per 256-thread block (7*34 = 238 active lanes)
#define BLOCK    256
#define VOCAB    14
#define QK_SCALE 0.5773502691896258f   // 1/sqrt(3)

__global__ __launch_bounds__(BLOCK) void addtrans_kernel(
    const int*   __restrict__ idx,      // (B, 34)
    const float* __restrict__ tok_emb,  // (14, 3)
    const float* __restrict__ pos_enc,  // (34, 3)
    const float* __restrict__ ln_w,     // (4, 6)
    const float* __restrict__ ln_b,     // (4, 6)
    const float* __restrict__ q1w,      // (4, 3, 3)
    const float* __restrict__ k1w,
    const float* __restrict__ v1w,
    const float* __restrict__ q2w,
    const float* __restrict__ k2w,
    const float* __restrict__ v2w,
    const float* __restrict__ out_w,    // (4, 6, 6)
    const float* __restrict__ lnf_w,    // (6,)
    const float* __restrict__ lnf_b,    // (6,)
    const float* __restrict__ head_w,   // (14, 6)
    float* __restrict__ out)            // (B, 34, 14)
{
    // K/V staging: transposed layout -> lane-consecutive writes (bank-conflict-free),
    // broadcast reads (all lanes of one batch element read the same address).
    __shared__ float kvs[12][NB * SEQ];

    const int  local    = threadIdx.x;
    const int  e_raw    = local / SEQ;         // magic-mul div by 34
    const int  t        = local - e_raw * SEQ; // 0..33 always
    const bool in_range = (e_raw < NB);
    const int  e        = in_range ? e_raw : (NB - 1);
    const int  b        = (int)blockIdx.x * NB + e;
    const bool active   = in_range && (b < BATCH_N);
    const int  bc       = (b < BATCH_N) ? b : (BATCH_N - 1);  // clamp for loads
    const int  row      = e * SEQ;             // base of this element's kv slot

    // ---- embedding: x = concat(tok_emb[idx], pos_enc[t]) ----
    float x[6];
    {
        const int tok = idx[(size_t)bc * SEQ + t];
        x[0] = tok_emb[tok * 3 + 0];
        x[1] = tok_emb[tok * 3 + 1];
        x[2] = tok_emb[tok * 3 + 2];
        x[3] = pos_enc[t * 3 + 0];
        x[4] = pos_enc[t * 3 + 1];
        x[5] = pos_enc[t * 3 + 2];
    }

    for (int l = 0; l < N_LAYERS; ++l) {
        // ---- layernorm (per-thread, D=6 in registers) ----
        float h[6];
        {
            float m = (x[0] + x[1] + x[2] + x[3] + x[4] + x[5]) * (1.0f / 6.0f);
            float var = 0.f;
            #pragma unroll
            for (int i = 0; i < 6; ++i) { float d = x[i] - m; var += d * d; }
            var *= (1.0f / 6.0f);
            float r = rsqrtf(var + 1e-5f);
            #pragma unroll
            for (int i = 0; i < 6; ++i)
                h[i] = (x[i] - m) * r * ln_w[l * 6 + i] + ln_b[l * 6 + i];
        }

        // ---- q/k/v projections: head1 from h[0:3], head2 from h[3:6] ----
        // weights indexed uniformly by l -> scalar loads, broadcast
        float q[6], kk[6], vv[6];
        #pragma unroll
        for (int i = 0; i < 3; ++i) {
            const int w = l * 9 + i * 3;
            q [i]     = q1w[w+0]*h[0] + q1w[w+1]*h[1] + q1w[w+2]*h[2];
            kk[i]     = k1w[w+0]*h[0] + k1w[w+1]*h[1] + k1w[w+2]*h[2];
            vv[i]     = v1w[w+0]*h[0] + v1w[w+1]*h[1] + v1w[w+2]*h[2];
            q [3 + i] = q2w[w+0]*h[3] + q2w[w+1]*h[4] + q2w[w+2]*h[5];
            kk[3 + i] = k2w[w+0]*h[3] + k2w[w+1]*h[4] + k2w[w+2]*h[5];
            vv[3 + i] = v2w[w+0]*h[3] + v2w[w+1]*h[4] + v2w[w+2]*h[5];
        }

        __syncthreads();   // previous layer's LDS reads must finish before overwrite
        if (in_range) {
            #pragma unroll
            for (int c = 0; c < 6; ++c) kvs[c][local]     = kk[c];
            #pragma unroll
            for (int c = 0; c < 6; ++c) kvs[6 + c][local] = vv[c];
        }
        __syncthreads();

        // ---- causal attention, 2 heads, two-pass softmax over LDS ----
        float o[6];
        #pragma unroll
        for (int hd = 0; hd < 2; ++hd) {
            const int qo = 3 * hd;       // K rows: qo..qo+2, V rows: 6+qo..8+qo
            const int vo = 6 + 3 * hd;
            float mx = -3.0e38f;
            for (int j = 0; j <= t; ++j) {
                float s = (q[qo+0] * kvs[qo+0][row + j] +
                           q[qo+1] * kvs[qo+1][row + j] +
                           q[qo+2] * kvs[qo+2][row + j]) * QK_SCALE;
                mx = fmaxf(mx, s);
            }
            float lsum = 0.f, a0 = 0.f, a1 = 0.f, a2 = 0.f;
            for (int j = 0; j <= t; ++j) {
                float s = (q[qo+0] * kvs[qo+0][row + j] +
                           q[qo+1] * kvs[qo+1][row + j] +
                           q[qo+2] * kvs[qo+2][row + j]) * QK_SCALE;
                float p = __expf(s - mx);
                lsum += p;
                a0 += p * kvs[vo+0][row + j];
                a1 += p * kvs[vo+1][row + j];
                a2 += p * kvs[vo+2][row + j];
            }
            const float inv = 1.0f / lsum;
            o[qo+0] = a0 * inv;
            o[qo+1] = a1 * inv;
            o[qo+2] = a2 * inv;
        }

        // ---- output projection + residual: x += o @ out_w[l]^T ----
        #pragma unroll
        for (int i = 0; i < 6; ++i) {
            const int w = l * 36 + i * 6;
            float u = out_w[w+0]*o[0] + out_w[w+1]*o[1] + out_w[w+2]*o[2]
                    + out_w[w+3]*o[3] + out_w[w+4]*o[4] + out_w[w+5]*o[5];
            x[i] += u;
        }
    }

    // ---- final layernorm ----
    float hf[6];
    {
        float m = (x[0] + x[1] + x[2] + x[3] + x[4] + x[5]) * (1.0f / 6.0f);
        float var = 0.f;
        #pragma unroll
        for (int i = 0; i < 6; ++i) { float d = x[i] - m; var += d * d; }
        var *= (1.0f / 6.0f);
        float r = rsqrtf(var + 1e-5f);
        #pragma unroll
        for (int i = 0; i < 6; ++i)
            hf[i] = (x[i] - m) * r * lnf_w[i] + lnf_b[i];
    }

    // ---- head: logits = hf @ head_w^T ----
    if (active) {
        const size_t base = ((size_t)b * SEQ + t) * VOCAB;
        #pragma unroll
        for (int c = 0; c < VOCAB; ++c) {
            const int w = c * 6;
            float s = head_w[w+0]*hf[0] + head_w[w+1]*hf[1] + head_w[w+2]*hf[2]
                    + head_w[w+3]*hf[3] + head_w[w+4]*hf[4] + head_w[w+5]*hf[5];
            out[base + c] = s;
        }
    }
}

extern "C" void kernel_launch(void* const* d_in, const int* in_sizes, int n_in,
                              void* d_out, int out_size, void* d_ws, size_t ws_size,
                              hipStream_t stream) {
    const int*   idx     = (const int*)  d_in[0];
    const float* tok_emb = (const float*)d_in[1];
    const float* pos_enc = (const float*)d_in[2];
    const float* ln_w    = (const float*)d_in[3];
    const float* ln_b    = (const float*)d_in[4];
    const float* q1w     = (const float*)d_in[5];
    const float* k1w     = (const float*)d_in[6];
    const float* v1w     = (const float*)d_in[7];
    const float* q2w     = (const float*)d_in[8];
    const float* k2w     = (const float*)d_in[9];
    const float* v2w     = (const float*)d_in[10];
    const float* out_w   = (const float*)d_in[11];
    const float* lnf_w   = (const float*)d_in[12];
    const float* lnf_b   = (const float*)d_in[13];
    const float* head_w  = (const float*)d_in[14];
    float* out = (float*)d_out;

    const int grid = (BATCH_N + NB - 1) / NB;   // 2341 blocks
    addtrans_kernel<<<grid, BLOCK, 0, stream>>>(
        idx, tok_emb, pos_enc, ln_w, ln_b,
        q1w, k1w, v1w, q2w, k2w, v2w,
        out_w, lnf_w, lnf_b, head_w, out);
}

// Round 2
// 148.574 us; speedup vs baseline: 1.4547x; 1.4547x over previous
//
#include <hip/hip_runtime.h>
#include <math.h>

#define N_LAYERS 4
#define SEQ      34
#define BATCH_N  16384
#define NE       16        // batch elements per block (threadIdx.x)
#define NSLOT    16        // position slots (threadIdx.y)
#define VOCAB    14
// (1/sqrt(3)) * log2(e): fold attention scale AND exp->exp2 conversion into q
#define QSCALE   0.8329806647638704f

__global__ __launch_bounds__(256) void addtrans_kernel(
    const int*   __restrict__ idx,      // (B, 34)
    const float* __restrict__ tok_emb,  // (14, 3)
    const float* __restrict__ pos_enc,  // (34, 3)
    const float* __restrict__ ln_w,     // (4, 6)
    const float* __restrict__ ln_b,     // (4, 6)
    const float* __restrict__ q1w,      // (4, 3, 3)
    const float* __restrict__ k1w,
    const float* __restrict__ v1w,
    const float* __restrict__ q2w,
    const float* __restrict__ k2w,
    const float* __restrict__ v2w,
    const float* __restrict__ out_w,    // (4, 6, 6)
    const float* __restrict__ lnf_w,    // (6,)
    const float* __restrict__ lnf_b,    // (6,)
    const float* __restrict__ head_w,   // (14, 6)
    float* __restrict__ out)            // (B, 34, 14)
{
    // K/V for one layer: per (t, e) 12 floats packed as 3 float4 chunks:
    //   chunk0 = {k0,k1,k2,k3}  chunk1 = {k4,k5,v0,v1}  chunk2 = {v2,v3,v4,v5}
    // layout [chunk*SEQ + t][e]: reads at fixed j are 16 consecutive float4
    // (4-way broadcast over slots) -> conflict-free; +1 row pad for prefetch.
    __shared__ float4 kvs[3 * SEQ + 1][NE];

    const int x = threadIdx.x;               // element within block
    const int y = threadIdx.y;               // slot
    const int b = (int)blockIdx.x * NE + x;  // batch element (grid divides exactly)

    // slot -> owned positions: {y, 33-y} for all slots (sum(t+1)=35, balanced),
    // slots 0,1 additionally own 16,17. tp==SEQ means "no position".
    int tp[3];
    tp[0] = y;
    tp[1] = 33 - y;
    tp[2] = (y < 2) ? (16 + y) : SEQ;

    // ---- embedding ----
    float xs[3][6];
    #pragma unroll
    for (int p = 0; p < 3; ++p) {
        const int t = tp[p];
        if (t < SEQ) {
            const int tok = idx[(size_t)b * SEQ + t];
            xs[p][0] = tok_emb[tok * 3 + 0];
            xs[p][1] = tok_emb[tok * 3 + 1];
            xs[p][2] = tok_emb[tok * 3 + 2];
            xs[p][3] = pos_enc[t * 3 + 0];
            xs[p][4] = pos_enc[t * 3 + 1];
            xs[p][5] = pos_enc[t * 3 + 2];
        }
    }

    float qs[3][6];

    for (int l = 0; l < N_LAYERS; ++l) {
        __syncthreads();   // WAR: previous layer's attention reads complete

        // ---- phase 1: LN + q/k/v projections, stage K/V to LDS ----
        #pragma unroll
        for (int p = 0; p < 3; ++p) {
            const int t = tp[p];
            if (t < SEQ) {
                float h[6];
                {
                    const float* v = xs[p];
                    float m = (v[0]+v[1]+v[2]+v[3]+v[4]+v[5]) * (1.0f/6.0f);
                    float var = 0.f;
                    #pragma unroll
                    for (int i = 0; i < 6; ++i) { float d = v[i]-m; var += d*d; }
                    var *= (1.0f/6.0f);
                    float r = rsqrtf(var + 1e-5f);
                    #pragma unroll
                    for (int i = 0; i < 6; ++i)
                        h[i] = (v[i]-m) * r * ln_w[l*6+i] + ln_b[l*6+i];
                }
                float kk[6], vv[6];
                #pragma unroll
                for (int i = 0; i < 3; ++i) {
                    const int w = l*9 + i*3;
                    qs[p][i]   = (q1w[w]*h[0] + q1w[w+1]*h[1] + q1w[w+2]*h[2]) * QSCALE;
                    kk[i]      =  k1w[w]*h[0] + k1w[w+1]*h[1] + k1w[w+2]*h[2];
                    vv[i]      =  v1w[w]*h[0] + v1w[w+1]*h[1] + v1w[w+2]*h[2];
                    qs[p][3+i] = (q2w[w]*h[3] + q2w[w+1]*h[4] + q2w[w+2]*h[5]) * QSCALE;
                    kk[3+i]    =  k2w[w]*h[3] + k2w[w+1]*h[4] + k2w[w+2]*h[5];
                    vv[3+i]    =  v2w[w]*h[3] + v2w[w+1]*h[4] + v2w[w+2]*h[5];
                }
                kvs[0*SEQ + t][x] = make_float4(kk[0], kk[1], kk[2], kk[3]);
                kvs[1*SEQ + t][x] = make_float4(kk[4], kk[5], vv[0], vv[1]);
                kvs[2*SEQ + t][x] = make_float4(vv[2], vv[3], vv[4], vv[5]);
            }
        }
        __syncthreads();   // RAW: K/V visible

        // ---- phase 2: causal attention (single-pass, no max: |s*log2e| < 46),
        //      output projection + residual ----
        #pragma unroll
        for (int p = 0; p < 3; ++p) {
            const int t = tp[p];
            if (t < SEQ) {
                const float q0 = qs[p][0], q1 = qs[p][1], q2 = qs[p][2];
                const float q3 = qs[p][3], q4 = qs[p][4], q5 = qs[p][5];
                float l1 = 0.f, l2 = 0.f;
                float a0 = 0.f, a1 = 0.f, a2 = 0.f, a3 = 0.f, a4 = 0.f, a5 = 0.f;
                float4 c0 = kvs[0][x], c1 = kvs[SEQ][x], c2 = kvs[2*SEQ][x];
                for (int j = 0; j <= t; ++j) {
                    float4 n0 = kvs[j + 1][x];
                    float4 n1 = kvs[SEQ + j + 1][x];
                    float4 n2 = kvs[2*SEQ + j + 1][x];
                    float s1 = q0*c0.x + q1*c0.y + q2*c0.z;
                    float s2 = q3*c0.w + q4*c1.x + q5*c1.y;
                    float p1 = __builtin_amdgcn_exp2f(s1);
                    float p2 = __builtin_amdgcn_exp2f(s2);
                    l1 += p1;        l2 += p2;
                    a0 += p1*c1.z;   a1 += p1*c1.w;   a2 += p1*c2.x;
                    a3 += p2*c2.y;   a4 += p2*c2.z;   a5 += p2*c2.w;
                    c0 = n0; c1 = n1; c2 = n2;
                }
                const float i1 = __builtin_amdgcn_rcpf(l1);
                const float i2 = __builtin_amdgcn_rcpf(l2);
                float o[6] = { a0*i1, a1*i1, a2*i1, a3*i2, a4*i2, a5*i2 };
                #pragma unroll
                for (int i = 0; i < 6; ++i) {
                    const int w = l*36 + i*6;
                    xs[p][i] += out_w[w+0]*o[0] + out_w[w+1]*o[1] + out_w[w+2]*o[2]
                              + out_w[w+3]*o[3] + out_w[w+4]*o[4] + out_w[w+5]*o[5];
                }
            }
        }
    }

    // ---- final layernorm + head ----
    #pragma unroll
    for (int p = 0; p < 3; ++p) {
        const int t = tp[p];
        if (t < SEQ) {
            float hf[6];
            {
                const float* v = xs[p];
                float m = (v[0]+v[1]+v[2]+v[3]+v[4]+v[5]) * (1.0f/6.0f);
                float var = 0.f;
                #pragma unroll
                for (int i = 0; i < 6; ++i) { float d = v[i]-m; var += d*d; }
                var *= (1.0f/6.0f);
                float r = rsqrtf(var + 1e-5f);
                #pragma unroll
                for (int i = 0; i < 6; ++i)
                    hf[i] = (v[i]-m) * r * lnf_w[i] + lnf_b[i];
            }
            float lg[VOCAB];
            #pragma unroll
            for (int c = 0; c < VOCAB; ++c) {
                const int w = c*6;
                lg[c] = head_w[w+0]*hf[0] + head_w[w+1]*hf[1] + head_w[w+2]*hf[2]
                      + head_w[w+3]*hf[3] + head_w[w+4]*hf[4] + head_w[w+5]*hf[5];
            }
            // 56-byte slot, 8B-aligned -> 7x float2 stores
            float2* op = (float2*)(out + ((size_t)b * SEQ + t) * VOCAB);
            #pragma unroll
            for (int c = 0; c < 7; ++c)
                op[c] = make_float2(lg[2*c], lg[2*c+1]);
        }
    }
}

extern "C" void kernel_launch(void* const* d_in, const int* in_sizes, int n_in,
                              void* d_out, int out_size, void* d_ws, size_t ws_size,
                              hipStream_t stream) {
    const int*   idx     = (const int*)  d_in[0];
    const float* tok_emb = (const float*)d_in[1];
    const float* pos_enc = (const float*)d_in[2];
    const float* ln_w    = (const float*)d_in[3];
    const float* ln_b    = (const float*)d_in[4];
    const float* q1w     = (const float*)d_in[5];
    const float* k1w     = (const float*)d_in[6];
    const float* v1w     = (const float*)d_in[7];
    const float* q2w     = (const float*)d_in[8];
    const float* k2w     = (const float*)d_in[9];
    const float* v2w     = (const float*)d_in[10];
    const float* out_w   = (const float*)d_in[11];
    const float* lnf_w   = (const float*)d_in[12];
    const float* lnf_b   = (const float*)d_in[13];
    const float* head_w  = (const float*)d_in[14];
    float* out = (float*)d_out;

    dim3 block(NE, NSLOT);
    const int grid = BATCH_N / NE;   // 1024 blocks
    addtrans_kernel<<<grid, block, 0, stream>>>(
        idx, tok_emb, pos_enc, ln_w, ln_b,
        q1w, k1w, v1w, q2w, k2w, v2w,
        out_w, lnf_w, lnf_b, head_w, out);
}

// Round 3
// 146.225 us; speedup vs baseline: 1.4780x; 1.0161x over previous
//
#include <hip/hip_runtime.h>
#include <math.h>

#define N_LAYERS 4
#define SEQ      34
#define BATCH_N  16384
#define NE       16        // batch elements per block (lane % 16)
#define NSLOT    8         // query slots per element (lane / 16)
#define NT       5         // max positions owned by one slot
#define VOCAB    14
// (1/sqrt(3)) * log2(e): fold attention scale AND exp->exp2 into q
#define QSCALE   0.8329806647638704f

__global__ __launch_bounds__(128) void addtrans_kernel(
    const int*   __restrict__ idx,      // (B, 34)
    const float* __restrict__ tok_emb,  // (14, 3)
    const float* __restrict__ pos_enc,  // (34, 3)
    const float* __restrict__ ln_w,     // (4, 6)
    const float* __restrict__ ln_b,     // (4, 6)
    const float* __restrict__ q1w,      // (4, 3, 3)
    const float* __restrict__ k1w,
    const float* __restrict__ v1w,
    const float* __restrict__ q2w,
    const float* __restrict__ k2w,
    const float* __restrict__ v2w,
    const float* __restrict__ out_w,    // (4, 6, 6)
    const float* __restrict__ lnf_w,    // (6,)
    const float* __restrict__ lnf_b,    // (6,)
    const float* __restrict__ head_w,   // (14, 6)
    float* __restrict__ out)            // (B, 34, 14)
{
    // K/V for one layer, packed 3 float4 per (t, e):
    //   chunk0={k0,k1,k2,k3} chunk1={k4,k5,v0,v1} chunk2={v2,v3,v4,v5}
    // layout [chunk*SEQ + t][e]; +1 row pad absorbs the j+1 prefetch overread.
    __shared__ float4 kvs[3 * SEQ + 1][NE];

    const int x = threadIdx.x & (NE - 1);      // element
    const int y = threadIdx.x >> 4;            // slot 0..7
    const int b = (int)blockIdx.x * NE + x;

    // slot y owns t = {jmax, y, 8+y, 16+y, 24+y?}; one merged j-loop to jmax
    // serves all of them (each LDS read amortized over 4-5 query rows).
    int tp[NT];
    tp[0] = (y < 2) ? (32 + y) : (24 + y);     // the longest row first (unconditional)
    tp[1] = y;
    tp[2] = 8 + y;
    tp[3] = 16 + y;
    tp[4] = (y < 2) ? (24 + y) : -1;           // -1 = absent
    const int jmax = tp[0];

    // ---- embedding ----
    float xs[NT][6];
    #pragma unroll
    for (int k = 0; k < NT; ++k) {
        const int t = tp[k];
        if (t >= 0) {
            const int tok = idx[(size_t)b * SEQ + t];
            xs[k][0] = tok_emb[tok * 3 + 0];
            xs[k][1] = tok_emb[tok * 3 + 1];
            xs[k][2] = tok_emb[tok * 3 + 2];
            xs[k][3] = pos_enc[t * 3 + 0];
            xs[k][4] = pos_enc[t * 3 + 1];
            xs[k][5] = pos_enc[t * 3 + 2];
        }
    }

    float qs[NT][6];

    for (int l = 0; l < N_LAYERS; ++l) {
        __syncthreads();   // WAR: previous layer's attention reads complete

        // ---- phase 1: LN + q/k/v projections for each owned t, stage K/V ----
        #pragma unroll
        for (int k = 0; k < NT; ++k) {
            const int t = tp[k];
            if (t >= 0) {
                float h[6];
                {
                    const float* v = xs[k];
                    float m = (v[0]+v[1]+v[2]+v[3]+v[4]+v[5]) * (1.0f/6.0f);
                    float var = 0.f;
                    #pragma unroll
                    for (int i = 0; i < 6; ++i) { float d = v[i]-m; var += d*d; }
                    var *= (1.0f/6.0f);
                    float r = rsqrtf(var + 1e-5f);
                    #pragma unroll
                    for (int i = 0; i < 6; ++i)
                        h[i] = (v[i]-m) * r * ln_w[l*6+i] + ln_b[l*6+i];
                }
                float kk[6], vv[6];
                #pragma unroll
                for (int i = 0; i < 3; ++i) {
                    const int w = l*9 + i*3;
                    qs[k][i]   = (q1w[w]*h[0] + q1w[w+1]*h[1] + q1w[w+2]*h[2]) * QSCALE;
                    kk[i]      =  k1w[w]*h[0] + k1w[w+1]*h[1] + k1w[w+2]*h[2];
                    vv[i]      =  v1w[w]*h[0] + v1w[w+1]*h[1] + v1w[w+2]*h[2];
                    qs[k][3+i] = (q2w[w]*h[3] + q2w[w+1]*h[4] + q2w[w+2]*h[5]) * QSCALE;
                    kk[3+i]    =  k2w[w]*h[3] + k2w[w+1]*h[4] + k2w[w+2]*h[5];
                    vv[3+i]    =  v2w[w]*h[3] + v2w[w+1]*h[4] + v2w[w+2]*h[5];
                }
                kvs[0*SEQ + t][x] = make_float4(kk[0], kk[1], kk[2], kk[3]);
                kvs[1*SEQ + t][x] = make_float4(kk[4], kk[5], vv[0], vv[1]);
                kvs[2*SEQ + t][x] = make_float4(vv[2], vv[3], vv[4], vv[5]);
            }
        }
        __syncthreads();   // RAW: K/V visible

        // ---- phase 2: merged causal attention over all owned t's ----
        // single-pass softmax (no max subtract: |s*log2e| < 46, fp32-safe)
        float l1[NT], l2[NT], a[NT][6];
        #pragma unroll
        for (int k = 0; k < NT; ++k) {
            l1[k] = 0.f; l2[k] = 0.f;
            #pragma unroll
            for (int i = 0; i < 6; ++i) a[k][i] = 0.f;
        }
        float4 c0 = kvs[0][x], c1 = kvs[SEQ][x], c2 = kvs[2*SEQ][x];
        #pragma unroll 2
        for (int j = 0; j <= jmax; ++j) {
            float4 n0 = kvs[j + 1][x];
            float4 n1 = kvs[SEQ + j + 1][x];
            float4 n2 = kvs[2*SEQ + j + 1][x];
            #pragma unroll
            for (int k = 0; k < NT; ++k) {
                if (k == 0 || j <= tp[k]) {   // k=0 unconditional; tp=-1 never fires
                    float s1 = qs[k][0]*c0.x + qs[k][1]*c0.y + qs[k][2]*c0.z;
                    float s2 = qs[k][3]*c0.w + qs[k][4]*c1.x + qs[k][5]*c1.y;
                    float p1 = __builtin_amdgcn_exp2f(s1);
                    float p2 = __builtin_amdgcn_exp2f(s2);
                    l1[k] += p1;        l2[k] += p2;
                    a[k][0] += p1*c1.z; a[k][1] += p1*c1.w; a[k][2] += p1*c2.x;
                    a[k][3] += p2*c2.y; a[k][4] += p2*c2.z; a[k][5] += p2*c2.w;
                }
            }
            c0 = n0; c1 = n1; c2 = n2;
        }

        // ---- epilogue: normalize, output projection + residual ----
        #pragma unroll
        for (int k = 0; k < NT; ++k) {
            if (tp[k] >= 0) {
                const float i1 = __builtin_amdgcn_rcpf(l1[k]);
                const float i2 = __builtin_amdgcn_rcpf(l2[k]);
                float o[6] = { a[k][0]*i1, a[k][1]*i1, a[k][2]*i1,
                               a[k][3]*i2, a[k][4]*i2, a[k][5]*i2 };
                #pragma unroll
                for (int i = 0; i < 6; ++i) {
                    const int w = l*36 + i*6;
                    xs[k][i] += out_w[w+0]*o[0] + out_w[w+1]*o[1] + out_w[w+2]*o[2]
                              + out_w[w+3]*o[3] + out_w[w+4]*o[4] + out_w[w+5]*o[5];
                }
            }
        }
    }

    // ---- final layernorm + head ----
    #pragma unroll
    for (int k = 0; k < NT; ++k) {
        const int t = tp[k];
        if (t >= 0) {
            float hf[6];
            {
                const float* v = xs[k];
                float m = (v[0]+v[1]+v[2]+v[3]+v[4]+v[5]) * (1.0f/6.0f);
                float var = 0.f;
                #pragma unroll
                for (int i = 0; i < 6; ++i) { float d = v[i]-m; var += d*d; }
                var *= (1.0f/6.0f);
                float r = rsqrtf(var + 1e-5f);
                #pragma unroll
                for (int i = 0; i < 6; ++i)
                    hf[i] = (v[i]-m) * r * lnf_w[i] + lnf_b[i];
            }
            float lg[VOCAB];
            #pragma unroll
            for (int c = 0; c < VOCAB; ++c) {
                const int w = c*6;
                lg[c] = head_w[w+0]*hf[0] + head_w[w+1]*hf[1] + head_w[w+2]*hf[2]
                      + head_w[w+3]*hf[3] + head_w[w+4]*hf[4] + head_w[w+5]*hf[5];
            }
            float2* op = (float2*)(out + ((size_t)b * SEQ + t) * VOCAB);
            #pragma unroll
            for (int c = 0; c < 7; ++c)
                op[c] = make_float2(lg[2*c], lg[2*c+1]);
        }
    }
}

extern "C" void kernel_launch(void* const* d_in, const int* in_sizes, int n_in,
                              void* d_out, int out_size, void* d_ws, size_t ws_size,
                              hipStream_t stream) {
    const int*   idx     = (const int*)  d_in[0];
    const float* tok_emb = (const float*)d_in[1];
    const float* pos_enc = (const float*)d_in[2];
    const float* ln_w    = (const float*)d_in[3];
    const float* ln_b    = (const float*)d_in[4];
    const float* q1w     = (const float*)d_in[5];
    const float* k1w     = (const float*)d_in[6];
    const float* v1w     = (const float*)d_in[7];
    const float* q2w     = (const float*)d_in[8];
    const float* k2w     = (const float*)d_in[9];
    const float* v2w     = (const float*)d_in[10];
    const float* out_w   = (const float*)d_in[11];
    const float* lnf_w   = (const float*)d_in[12];
    const float* lnf_b   = (const float*)d_in[13];
    const float* head_w  = (const float*)d_in[14];
    float* out = (float*)d_out;

    const int grid = BATCH_N / NE;   // 1024 blocks of 128 threads
    addtrans_kernel<<<grid, NE * NSLOT, 0, stream>>>(
        idx, tok_emb, pos_enc, ln_w, ln_b,
        q1w, k1w, v1w, q2w, k2w, v2w,
        out_w, lnf_w, lnf_b, head_w, out);
}